// Round 1
// baseline (1418.322 us; speedup 1.0000x reference)
//
#include <hip/hip_runtime.h>
#include <cstdint>
#include <cstddef>

// Problem geometry
#define T_N   500
#define B_N   16
#define F_IN  6300
#define KW    197          // 197 words * 32 bits = 6304 (K padded)
#define H1    1024
#define H2    20
#define M_N   8000         // T*B rows, m = t*16 + b
#define M_PADN 8064        // 63 * 128

// SLAYER constants (match jnp.float32(np.exp(-1.0)) etc.)
#define DD_C   0.36787944117144233f   // exp(-1)
#define CC_C   2.718281828459045f     // e / tau
#define THETA_C 10.0f

// ---------------------------------------------------------------------------
// Kernel 1: pack input spikes (B,F,T) -> bitmask rows m=(t*16+b), 197 words
// ---------------------------------------------------------------------------
__global__ void prep_bits_k(const float* __restrict__ in, uint32_t* __restrict__ bits) {
    const int tch = blockIdx.x;   // 0..7   (t chunk of 64)
    const int w   = blockIdx.y;   // 0..196 (32-feature word)
    const int b   = blockIdx.z;   // 0..15
    const int t   = tch * 64 + threadIdx.x;   // 0..511
    if (t >= 504) return;                      // rows only alloc'd to 8063
    const int m = t * 16 + b;                  // < 8064
    uint32_t word = 0u;
    if (t < T_N) {
        const int fbase = w * 32;
        #pragma unroll
        for (int j = 0; j < 32; ++j) {
            const int f = fbase + j;
            float v = 0.f;
            if (f < F_IN) v = in[((size_t)b * F_IN + f) * T_N + t];
            word |= (v != 0.f ? 1u : 0u) << j;
        }
    }
    bits[(size_t)m * KW + w] = word;   // zero rows for t in [500,504)
}

// ---------------------------------------------------------------------------
// Kernel 2: transpose w1 (1024,6300) -> w1t (6304,1024), pad rows zeroed
// ---------------------------------------------------------------------------
__global__ void transpose_w1_k(const float* __restrict__ w1, float* __restrict__ w1t) {
    __shared__ float tile[32][33];
    const int f0 = blockIdx.x * 32;   // 0..6272
    const int o0 = blockIdx.y * 32;
    const int tx = threadIdx.x;       // 0..31
    const int ty = threadIdx.y;       // 0..7
    #pragma unroll
    for (int r = 0; r < 32; r += 8) {
        const int o = o0 + ty + r;
        const int f = f0 + tx;
        tile[ty + r][tx] = (f < F_IN) ? w1[(size_t)o * F_IN + f] : 0.f;
    }
    __syncthreads();
    #pragma unroll
    for (int r = 0; r < 32; r += 8) {
        const int f = f0 + ty + r;   // < 6304
        const int o = o0 + tx;
        w1t[(size_t)f * H1 + o] = tile[tx][ty + r];
    }
}

// ---------------------------------------------------------------------------
// Kernel 3: GEMM1 (fp32): u1[m][o] = sum_f x[m][f] * w1t[f][o]
//   A from bitmask (exact 0/1), 128x128 tile, 8x8 microtile, K-step 32
// ---------------------------------------------------------------------------
__global__ __launch_bounds__(256, 2)
void gemm1_k(const uint32_t* __restrict__ bits, const float* __restrict__ w1t,
             float* __restrict__ u1) {
    __shared__ float As[32][128];   // [k][m]
    __shared__ float Bs[32][128];   // [k][n]
    const int n0 = blockIdx.x * 128;   // x = n-tile -> one XCD per B-panel
    const int m0 = blockIdx.y * 128;
    const int tid = threadIdx.x;
    const int tm = tid >> 4;    // 0..15 (m micro)
    const int tn = tid & 15;    // 0..15 (n micro) -> coalesced stores
    float acc[8][8];
    #pragma unroll
    for (int i = 0; i < 8; ++i)
        #pragma unroll
        for (int j = 0; j < 8; ++j) acc[i][j] = 0.f;

    for (int kw = 0; kw < KW; ++kw) {
        __syncthreads();
        // A: 128 rows x 1 word -> unpack 32 k's
        if (tid < 128) {
            const uint32_t wrd = bits[(size_t)(m0 + tid) * KW + kw];
            #pragma unroll
            for (int j = 0; j < 32; ++j)
                As[j][tid] = ((wrd >> j) & 1u) ? 1.f : 0.f;
        }
        // B: 32x128 floats, coalesced float4
        #pragma unroll
        for (int p = 0; p < 4; ++p) {
            const int i4 = tid + p * 256;      // 0..1023 float4 slots
            const int k  = i4 >> 5;
            const int c  = (i4 & 31) << 2;
            *(float4*)&Bs[k][c] =
                *(const float4*)&w1t[(size_t)(kw * 32 + k) * H1 + n0 + c];
        }
        __syncthreads();
        #pragma unroll 4
        for (int k = 0; k < 32; ++k) {
            float a[8], bb[8];
            *(float4*)&a[0]  = *(float4*)&As[k][tm * 8];
            *(float4*)&a[4]  = *(float4*)&As[k][tm * 8 + 4];
            *(float4*)&bb[0] = *(float4*)&Bs[k][tn * 8];
            *(float4*)&bb[4] = *(float4*)&Bs[k][tn * 8 + 4];
            #pragma unroll
            for (int i = 0; i < 8; ++i)
                #pragma unroll
                for (int j = 0; j < 8; ++j)
                    acc[i][j] += a[i] * bb[j];
        }
    }
    #pragma unroll
    for (int i = 0; i < 8; ++i) {
        const int m = m0 + tm * 8 + i;
        if (m < M_N) {
            float* dst = &u1[(size_t)m * H1 + n0 + tn * 8];
            *(float4*)dst       = make_float4(acc[i][0], acc[i][1], acc[i][2], acc[i][3]);
            *(float4*)(dst + 4) = make_float4(acc[i][4], acc[i][5], acc[i][6], acc[i][7]);
        }
    }
}

// ---------------------------------------------------------------------------
// Kernel 4: fused psp1 + spike_dyn1 over T (16384 lanes), pipelined loads
// ---------------------------------------------------------------------------
__global__ void scan1_k(const float* __restrict__ u1, float* __restrict__ s1) {
    const int lane = blockIdx.x * 256 + threadIdx.x;   // 0..16383
    const float CREF = -20.0f * CC_C;
    float p1 = 0.f, q1 = 0.f, pr = 0.f, qr = 0.f;
    float A[10], Bv[10];

#define STEP1(xv, tidx) {                                   \
        q1 = DD_C * (q1 + p1); p1 = DD_C * p1 + (xv);       \
        const float uu = CC_C * q1;                         \
        qr = DD_C * (qr + pr);                              \
        const float vv = uu + CREF * qr - THETA_C;          \
        const float ss = (vv >= 0.f) ? 1.f : 0.f;           \
        pr = DD_C * pr + ss;                                \
        s1[(size_t)(tidx) * 16384 + lane] = ss; }

    #pragma unroll
    for (int j = 0; j < 10; ++j) A[j] = u1[(size_t)j * 16384 + lane];
    for (int it = 0; it < 25; ++it) {
        const int gB = 2 * it + 1;
        #pragma unroll
        for (int j = 0; j < 10; ++j) Bv[j] = u1[(size_t)(gB * 10 + j) * 16384 + lane];
        #pragma unroll
        for (int j = 0; j < 10; ++j) STEP1(A[j], (2 * it) * 10 + j);
        if (it < 24) {
            const int gA = 2 * it + 2;
            #pragma unroll
            for (int j = 0; j < 10; ++j) A[j] = u1[(size_t)(gA * 10 + j) * 16384 + lane];
        }
        #pragma unroll
        for (int j = 0; j < 10; ++j) STEP1(Bv[j], gB * 10 + j);
    }
#undef STEP1
}

// ---------------------------------------------------------------------------
// Kernel 5: GEMM2 (fp32): u2[m][o2] = sum_h s1[m][h]*w2[o2][h]; one t per block
// ---------------------------------------------------------------------------
__global__ void gemm2_k(const float* __restrict__ s1, const float* __restrict__ w2,
                        float* __restrict__ u2) {
    __shared__ float sS[16][129];
    __shared__ float sW[20][129];
    const int t = blockIdx.x;
    const int tid = threadIdx.x;     // 0..319
    const int mi = tid & 15;         // batch
    const int o2 = tid >> 4;         // 0..19
    float acc = 0.f;
    for (int hc = 0; hc < 8; ++hc) {
        __syncthreads();
        for (int i = tid; i < 16 * 128; i += 320)
            sS[i >> 7][i & 127] = s1[(size_t)t * 16384 + (size_t)(i >> 7) * 1024 + hc * 128 + (i & 127)];
        for (int i = tid; i < 20 * 128; i += 320)
            sW[i >> 7][i & 127] = w2[(size_t)(i >> 7) * 1024 + hc * 128 + (i & 127)];
        __syncthreads();
        #pragma unroll 8
        for (int h = 0; h < 128; ++h)
            acc += sS[mi][h] * sW[o2][h];
    }
    u2[(size_t)(t * 16 + mi) * 20 + o2] = acc;
}

// ---------------------------------------------------------------------------
// Kernel 6: fused psp2 + spike_dyn2 (320 lanes) + transposed output write
// ---------------------------------------------------------------------------
__global__ void scan2_k(const float* __restrict__ u2, float* __restrict__ out) {
    const int lane = threadIdx.x;    // 0..319 = b*20 + o2
    const float CREF = -20.0f * CC_C;
    float p1 = 0.f, q1 = 0.f, pr = 0.f, qr = 0.f;
    float A[10], Bv[10];

#define STEP2(xv, tidx) {                                   \
        q1 = DD_C * (q1 + p1); p1 = DD_C * p1 + (xv);       \
        const float uu = CC_C * q1;                         \
        qr = DD_C * (qr + pr);                              \
        const float vv = uu + CREF * qr - THETA_C;          \
        const float ss = (vv >= 0.f) ? 1.f : 0.f;           \
        pr = DD_C * pr + ss;                                \
        out[(size_t)lane * T_N + (tidx)] = ss; }

    #pragma unroll
    for (int j = 0; j < 10; ++j) A[j] = u2[(size_t)j * 320 + lane];
    for (int it = 0; it < 25; ++it) {
        const int gB = 2 * it + 1;
        #pragma unroll
        for (int j = 0; j < 10; ++j) Bv[j] = u2[(size_t)(gB * 10 + j) * 320 + lane];
        #pragma unroll
        for (int j = 0; j < 10; ++j) STEP2(A[j], (2 * it) * 10 + j);
        if (it < 24) {
            const int gA = 2 * it + 2;
            #pragma unroll
            for (int j = 0; j < 10; ++j) A[j] = u2[(size_t)(gA * 10 + j) * 320 + lane];
        }
        #pragma unroll
        for (int j = 0; j < 10; ++j) STEP2(Bv[j], gB * 10 + j);
    }
#undef STEP2
}

// ---------------------------------------------------------------------------
extern "C" void kernel_launch(void* const* d_in, const int* in_sizes, int n_in,
                              void* d_out, int out_size, void* d_ws, size_t ws_size,
                              hipStream_t stream) {
    const float* x  = (const float*)d_in[0];   // (16,2,50,63,500) binary
    const float* w1 = (const float*)d_in[1];   // (1024,6300)
    const float* w2 = (const float*)d_in[2];   // (20,1024)
    float* out = (float*)d_out;                // (16,20,500)

    char* ws = (char*)d_ws;
    size_t off = 0;
    uint32_t* bits = (uint32_t*)(ws + off); off += (size_t)M_PADN * KW * 4;      //  6.35 MB
    float*    w1t  = (float*)(ws + off);    off += (size_t)6304 * H1 * 4;        // 25.82 MB
    float*    u1   = (float*)(ws + off);    off += (size_t)M_N * H1 * 4;         // 32.77 MB
    float*    s1   = (float*)(ws + off);    off += (size_t)M_N * H1 * 4;         // 32.77 MB
    float*    u2   = (float*)(ws + off);    off += (size_t)M_N * H2 * 4;         //  0.64 MB
    (void)ws_size; (void)in_sizes; (void)n_in; (void)out_size;

    prep_bits_k   <<<dim3(8, KW, B_N), 64,          0, stream>>>(x, bits);
    transpose_w1_k<<<dim3(KW, 32),     dim3(32, 8), 0, stream>>>(w1, w1t);
    gemm1_k       <<<dim3(8, 63),      256,         0, stream>>>(bits, w1t, u1);
    scan1_k       <<<64,               256,         0, stream>>>(u1, s1);
    gemm2_k       <<<T_N,              320,         0, stream>>>(s1, w2, u2);
    scan2_k       <<<1,                320,         0, stream>>>(u2, out);
}

// Round 2
// 511.319 us; speedup vs baseline: 2.7738x; 2.7738x over previous
//
#include <hip/hip_runtime.h>
#include <cstdint>
#include <cstddef>

// Problem geometry
#define T_N   500
#define B_N   16
#define F_IN  6300
#define KW    197          // 197 words * 32 bits = 6304 (K padded)
#define KPAD  6304
#define H1    1024
#define H2    20
#define M_N   8000         // T*B rows, m = t*16 + b
#define M_PADN 8064        // 63 * 128

// SLAYER constants
#define DD_C   0.36787944117144233f   // exp(-1)
#define CC_C   2.718281828459045f     // e / tau
#define THETA_C 10.0f

typedef __attribute__((ext_vector_type(8))) short short8;   // 8 bf16 (4 VGPRs)
typedef __attribute__((ext_vector_type(4))) float f32x4;

// ---------------------------------------------------------------------------
// bf16 round-to-nearest-even helpers (manual, dependency-free)
// ---------------------------------------------------------------------------
__device__ __forceinline__ unsigned short f2bf(float f) {
    union { float f; uint32_t u; } c; c.f = f;
    uint32_t u = c.u;
    uint32_t r = (u + 0x7FFFu + ((u >> 16) & 1u)) >> 16;
    return (unsigned short)r;
}
__device__ __forceinline__ float bf2f(unsigned short h) {
    union { uint32_t u; float f; } c; c.u = ((uint32_t)h) << 16;
    return c.f;
}

// ---------------------------------------------------------------------------
// Kernel 1: pack input spikes (B,F,T) -> bits_t[kw][m], m=(t*16+b), kw word
// ---------------------------------------------------------------------------
__global__ void prep_bits_t_k(const float* __restrict__ in, uint32_t* __restrict__ bits_t) {
    const int tch = blockIdx.x;   // 0..7   (t chunk of 64)
    const int w   = blockIdx.y;   // 0..196 (32-feature word)
    const int b   = blockIdx.z;   // 0..15
    const int t   = tch * 64 + threadIdx.x;   // 0..511
    if (t >= 504) return;
    const int m = t * 16 + b;                  // < 8064
    uint32_t word = 0u;
    if (t < T_N) {
        const int fbase = w * 32;
        #pragma unroll
        for (int j = 0; j < 32; ++j) {
            const int f = fbase + j;
            float v = 0.f;
            if (f < F_IN) v = in[((size_t)b * F_IN + f) * T_N + t];
            word |= (v != 0.f ? 1u : 0u) << j;
        }
    }
    bits_t[(size_t)w * M_PADN + m] = word;   // zero rows for t in [500,504)
}

// ---------------------------------------------------------------------------
// Kernel 2: split w1 (1024,6300) fp32 -> w3[3][1024][6304] bf16 (hi/mid/lo)
// ---------------------------------------------------------------------------
__global__ void split3_w1_k(const float* __restrict__ w1, unsigned short* __restrict__ w3) {
    const int o = blockIdx.y;                         // 0..1023
    const int f = blockIdx.x * 256 + threadIdx.x;     // 0..6399
    if (f >= KPAD) return;
    float w = (f < F_IN) ? w1[(size_t)o * F_IN + f] : 0.f;
    const unsigned short h1 = f2bf(w);
    const float r1 = w - bf2f(h1);
    const unsigned short h2 = f2bf(r1);
    const float r2 = r1 - bf2f(h2);
    const unsigned short h3 = f2bf(r2);
    const size_t base = (size_t)o * KPAD + f;
    w3[base]                           = h1;
    w3[(size_t)H1 * KPAD + base]       = h2;
    w3[(size_t)2 * H1 * KPAD + base]   = h3;
}

// ---------------------------------------------------------------------------
// Kernel 3: GEMM1 via MFMA bf16, 3-term split accumulation.
//   u1[m][o] = sum_f A[m][f] * (h1+h2+h3)[o][f]
//   Tile 128x128, BK=32 (one bit-word), 4 waves (2x2), 16x16x32 MFMA.
//   A-tile: bits unpacked to LDS bf16 [128][32], chunk16 XOR-swizzled by (row>>1)&3
//   B-tile: global_load_lds width=16, linear LDS [term][128][32]
//   Fragment reads: ds_read_b128 at [row][ (lane>>4)*16 ], identical phys k-order
//   for A and B  ->  internal MFMA k-permutation cancels (layout-agnostic).
// ---------------------------------------------------------------------------
__global__ __launch_bounds__(256)
void gemm1_mfma_k(const uint32_t* __restrict__ bits_t,
                  const unsigned short* __restrict__ w3,
                  float* __restrict__ u1) {
    __shared__ uint32_t AsU[128 * 16];        // 8 KB : [row][16 u32]
    __shared__ uint32_t BsU[3 * 128 * 16];    // 24 KB: [term][row(o)][16 u32]

    const int tid  = threadIdx.x;
    const int lane = tid & 63;
    const int wave = tid >> 6;
    const int wr = wave >> 1, wc = wave & 1;
    const int n0 = blockIdx.x * 128;          // x = n-tile -> XCD-exclusive B panel
    const int m0 = blockIdx.y * 128;
    const int l15 = lane & 15, g = lane >> 4;

    // B global source per-lane base: 16 contiguous bytes per lane
    const unsigned short* bsrc0 =
        w3 + (size_t)(n0 + (lane >> 2)) * KPAD + (lane & 3) * 8;

    // A staging mapping: thread -> (row, k-half)
    const int arow_w = tid & 127;
    const int ah     = tid >> 7;              // 0/1
    const int axor   = (arow_w >> 1) & 3;
    const int apos0  = (2 * ah) ^ axor;
    const int apos1  = (2 * ah + 1) ^ axor;

    f32x4 acc[4][4];
    const f32x4 fz = {0.f, 0.f, 0.f, 0.f};
    #pragma unroll
    for (int i = 0; i < 4; ++i)
        #pragma unroll
        for (int j = 0; j < 4; ++j) acc[i][j] = fz;

    // fragment LDS offsets (in u32 units)
    int aoff[4], boff[4];
    #pragma unroll
    for (int mi = 0; mi < 4; ++mi) {
        const int ar = wr * 64 + mi * 16 + l15;
        aoff[mi] = ar * 16 + ((g ^ ((ar >> 1) & 3)) << 2);
    }
    #pragma unroll
    for (int ni = 0; ni < 4; ++ni) {
        const int br = wc * 64 + ni * 16 + l15;
        boff[ni] = br * 16 + (g << 2);
    }

    for (int kw = 0; kw < KW; ++kw) {
        __syncthreads();
        // ---- stage B: 24 global_load_lds x 16B, 6 per wave ----
        #pragma unroll
        for (int j = 0; j < 6; ++j) {
            const int e    = wave * 6 + j;    // 0..23
            const int term = e >> 3;
            const int ii   = e & 7;           // 16-row slab
            const unsigned short* src =
                bsrc0 + (size_t)(term * H1 + ii * 16) * KPAD + kw * 32;
            __builtin_amdgcn_global_load_lds(
                (const __attribute__((address_space(1))) uint32_t*)src,
                (__attribute__((address_space(3))) uint32_t*)&BsU[term * 2048 + ii * 256],
                16, 0, 0);
        }
        // ---- stage A: unpack one bit-word half per thread ----
        {
            const uint32_t word = bits_t[(size_t)kw * M_PADN + m0 + arow_w];
            uint32_t v[8];
            #pragma unroll
            for (int i = 0; i < 8; ++i) {
                const int b0 = ah * 16 + 2 * i;
                v[i] = (((word >> b0) & 1u) ? 0x00003F80u : 0u) |
                       (((word >> (b0 + 1)) & 1u) ? 0x3F800000u : 0u);
            }
            *(uint4*)&AsU[arow_w * 16 + apos0 * 4] = make_uint4(v[0], v[1], v[2], v[3]);
            *(uint4*)&AsU[arow_w * 16 + apos1 * 4] = make_uint4(v[4], v[5], v[6], v[7]);
        }
        __syncthreads();   // compiler drains vmcnt+lgkmcnt here

        // ---- compute: 4 A-frags, then per term 4 B-frags + 16 MFMA ----
        short8 af[4];
        #pragma unroll
        for (int mi = 0; mi < 4; ++mi) af[mi] = *(const short8*)&AsU[aoff[mi]];
        #pragma unroll
        for (int term = 0; term < 3; ++term) {
            short8 bfv[4];
            #pragma unroll
            for (int ni = 0; ni < 4; ++ni)
                bfv[ni] = *(const short8*)&BsU[term * 2048 + boff[ni]];
            #pragma unroll
            for (int mi = 0; mi < 4; ++mi)
                #pragma unroll
                for (int ni = 0; ni < 4; ++ni)
                    acc[mi][ni] = __builtin_amdgcn_mfma_f32_16x16x32_bf16(
                        af[mi], bfv[ni], acc[mi][ni], 0, 0, 0);
        }
    }

    // ---- epilogue: D layout col=lane&15, row=(lane>>4)*4+r (m89-verified) ----
    #pragma unroll
    for (int mi = 0; mi < 4; ++mi) {
        const int mbase = m0 + wr * 64 + mi * 16 + g * 4;
        #pragma unroll
        for (int ni = 0; ni < 4; ++ni) {
            const int o = n0 + wc * 64 + ni * 16 + l15;
            #pragma unroll
            for (int r = 0; r < 4; ++r)
                u1[(size_t)(mbase + r) * H1 + o] = acc[mi][ni][r];
        }
    }
}

// ---------------------------------------------------------------------------
// Kernel 4: fused psp1 + spike_dyn1 over T (16384 lanes), pipelined loads
// ---------------------------------------------------------------------------
__global__ void scan1_k(const float* __restrict__ u1, float* __restrict__ s1) {
    const int lane = blockIdx.x * 256 + threadIdx.x;   // 0..16383
    const float CREF = -20.0f * CC_C;
    float p1 = 0.f, q1 = 0.f, pr = 0.f, qr = 0.f;
    float A[10], Bv[10];

#define STEP1(xv, tidx) {                                   \
        q1 = DD_C * (q1 + p1); p1 = DD_C * p1 + (xv);       \
        const float uu = CC_C * q1;                         \
        qr = DD_C * (qr + pr);                              \
        const float vv = uu + CREF * qr - THETA_C;          \
        const float ss = (vv >= 0.f) ? 1.f : 0.f;           \
        pr = DD_C * pr + ss;                                \
        s1[(size_t)(tidx) * 16384 + lane] = ss; }

    #pragma unroll
    for (int j = 0; j < 10; ++j) A[j] = u1[(size_t)j * 16384 + lane];
    for (int it = 0; it < 25; ++it) {
        const int gB = 2 * it + 1;
        #pragma unroll
        for (int j = 0; j < 10; ++j) Bv[j] = u1[(size_t)(gB * 10 + j) * 16384 + lane];
        #pragma unroll
        for (int j = 0; j < 10; ++j) STEP1(A[j], (2 * it) * 10 + j);
        if (it < 24) {
            const int gA = 2 * it + 2;
            #pragma unroll
            for (int j = 0; j < 10; ++j) A[j] = u1[(size_t)(gA * 10 + j) * 16384 + lane];
        }
        #pragma unroll
        for (int j = 0; j < 10; ++j) STEP1(Bv[j], gB * 10 + j);
    }
#undef STEP1
}

// ---------------------------------------------------------------------------
// Kernel 5: GEMM2 (fp32): u2[m][o2] = sum_h s1[m][h]*w2[o2][h]; one t per block
// ---------------------------------------------------------------------------
__global__ void gemm2_k(const float* __restrict__ s1, const float* __restrict__ w2,
                        float* __restrict__ u2) {
    __shared__ float sS[16][129];
    __shared__ float sW[20][129];
    const int t = blockIdx.x;
    const int tid = threadIdx.x;     // 0..319
    const int mi = tid & 15;         // batch
    const int o2 = tid >> 4;         // 0..19
    float acc = 0.f;
    for (int hc = 0; hc < 8; ++hc) {
        __syncthreads();
        for (int i = tid; i < 16 * 128; i += 320)
            sS[i >> 7][i & 127] = s1[(size_t)t * 16384 + (size_t)(i >> 7) * 1024 + hc * 128 + (i & 127)];
        for (int i = tid; i < 20 * 128; i += 320)
            sW[i >> 7][i & 127] = w2[(size_t)(i >> 7) * 1024 + hc * 128 + (i & 127)];
        __syncthreads();
        #pragma unroll 8
        for (int h = 0; h < 128; ++h)
            acc += sS[mi][h] * sW[o2][h];
    }
    u2[(size_t)(t * 16 + mi) * 20 + o2] = acc;
}

// ---------------------------------------------------------------------------
// Kernel 6: fused psp2 + spike_dyn2 (320 lanes) + transposed output write
// ---------------------------------------------------------------------------
__global__ void scan2_k(const float* __restrict__ u2, float* __restrict__ out) {
    const int lane = threadIdx.x;    // 0..319 = b*20 + o2
    const float CREF = -20.0f * CC_C;
    float p1 = 0.f, q1 = 0.f, pr = 0.f, qr = 0.f;
    float A[10], Bv[10];

#define STEP2(xv, tidx) {                                   \
        q1 = DD_C * (q1 + p1); p1 = DD_C * p1 + (xv);       \
        const float uu = CC_C * q1;                         \
        qr = DD_C * (qr + pr);                              \
        const float vv = uu + CREF * qr - THETA_C;          \
        const float ss = (vv >= 0.f) ? 1.f : 0.f;           \
        pr = DD_C * pr + ss;                                \
        out[(size_t)lane * T_N + (tidx)] = ss; }

    #pragma unroll
    for (int j = 0; j < 10; ++j) A[j] = u2[(size_t)j * 320 + lane];
    for (int it = 0; it < 25; ++it) {
        const int gB = 2 * it + 1;
        #pragma unroll
        for (int j = 0; j < 10; ++j) Bv[j] = u2[(size_t)(gB * 10 + j) * 320 + lane];
        #pragma unroll
        for (int j = 0; j < 10; ++j) STEP2(A[j], (2 * it) * 10 + j);
        if (it < 24) {
            const int gA = 2 * it + 2;
            #pragma unroll
            for (int j = 0; j < 10; ++j) A[j] = u2[(size_t)(gA * 10 + j) * 320 + lane];
        }
        #pragma unroll
        for (int j = 0; j < 10; ++j) STEP2(Bv[j], gB * 10 + j);
    }
#undef STEP2
}

// ---------------------------------------------------------------------------
extern "C" void kernel_launch(void* const* d_in, const int* in_sizes, int n_in,
                              void* d_out, int out_size, void* d_ws, size_t ws_size,
                              hipStream_t stream) {
    const float* x  = (const float*)d_in[0];   // (16,2,50,63,500) binary
    const float* w1 = (const float*)d_in[1];   // (1024,6300)
    const float* w2 = (const float*)d_in[2];   // (20,1024)
    float* out = (float*)d_out;                // (16,20,500)

    char* ws = (char*)d_ws;
    size_t off = 0;
    uint32_t*       bits_t = (uint32_t*)(ws + off);       off += (size_t)KW * M_PADN * 4;      //  6.35 MB
    unsigned short* w3     = (unsigned short*)(ws + off); off += (size_t)3 * H1 * KPAD * 2;    // 38.73 MB
    float*          u1     = (float*)(ws + off);          off += (size_t)M_PADN * H1 * 4;      // 33.03 MB
    float*          s1     = (float*)(ws + off);          off += (size_t)M_N * H1 * 4;         // 32.77 MB
    float*          u2     = (float*)(ws + off);          off += (size_t)M_N * H2 * 4;         //  0.64 MB
    (void)ws_size; (void)in_sizes; (void)n_in; (void)out_size;

    prep_bits_t_k <<<dim3(8, KW, B_N), 64,  0, stream>>>(x, bits_t);
    split3_w1_k   <<<dim3(25, H1),     256, 0, stream>>>(w1, w3);
    gemm1_mfma_k  <<<dim3(8, 63),      256, 0, stream>>>(bits_t, w3, u1);
    scan1_k       <<<64,               256, 0, stream>>>(u1, s1);
    gemm2_k       <<<T_N,              320, 0, stream>>>(s1, w2, u2);
    scan2_k       <<<1,                320, 0, stream>>>(u2, out);
}

// Round 3
// 353.522 us; speedup vs baseline: 4.0120x; 1.4464x over previous
//
#include <hip/hip_runtime.h>
#include <cstdint>
#include <cstddef>

// Problem geometry
#define T_N   500
#define B_N   16
#define F_IN  6300
#define KW    198          // 198 words * 32 bits = 6336 (K padded)
#define KPAD  6336
#define H1    1024
#define H2    20
#define N2P   32           // gemm2 N padded 20 -> 32
#define M_N   8000         // T*B rows, m = t*16 + b
#define M_PADN 8064        // 63 * 128

// SLAYER constants
#define DD_C   0.36787944117144233f   // exp(-1)
#define CC_C   2.718281828459045f     // e / tau
#define THETA_C 10.0f
#define INV2048 4.8828125e-4f

typedef _Float16 half8 __attribute__((ext_vector_type(8)));
typedef __attribute__((ext_vector_type(4))) float f32x4;

__device__ __forceinline__ unsigned short f2h_bits(float x) {
    union { _Float16 h; unsigned short u; } c; c.h = (_Float16)x; return c.u;
}
__device__ __forceinline__ float h2f(unsigned short u) {
    union { _Float16 h; unsigned short u; } c; c.u = u; return (float)c.h;
}

// ---------------------------------------------------------------------------
// Kernel 1: pack input spikes (B,F,T) -> bits_t[kw][m], m=(t*16+b)
// ---------------------------------------------------------------------------
__global__ void prep_bits_t_k(const float* __restrict__ in, uint32_t* __restrict__ bits_t) {
    const int tch = blockIdx.x;   // 0..7
    const int w   = blockIdx.y;   // 0..197
    const int b   = blockIdx.z;   // 0..15
    const int t   = tch * 64 + threadIdx.x;
    if (t >= 504) return;
    const int m = t * 16 + b;
    uint32_t word = 0u;
    if (t < T_N) {
        const int fbase = w * 32;
        #pragma unroll
        for (int j = 0; j < 32; ++j) {
            const int f = fbase + j;
            float v = 0.f;
            if (f < F_IN) v = in[((size_t)b * F_IN + f) * T_N + t];
            word |= (v != 0.f ? 1u : 0u) << j;
        }
    }
    bits_t[(size_t)w * M_PADN + m] = word;
}

// ---------------------------------------------------------------------------
// Kernel 2a: split w1 fp32 -> w1f[2][1024][6336] fp16; term1 = fp16(w),
//            term2 = fp16((w - term1) * 2048)  (scaled to dodge subnormals)
// ---------------------------------------------------------------------------
__global__ void split2_w1_k(const float* __restrict__ w1, unsigned short* __restrict__ w1f) {
    const int o = blockIdx.y;                         // 0..1023
    const int f = blockIdx.x * 256 + threadIdx.x;     // 0..6399
    if (f >= KPAD) return;
    float w = (f < F_IN) ? w1[(size_t)o * F_IN + f] : 0.f;
    const unsigned short h1 = f2h_bits(w);
    const float r1 = w - h2f(h1);
    const unsigned short h2 = f2h_bits(r1 * 2048.0f);
    const size_t base = (size_t)o * KPAD + f;
    w1f[base]                      = h1;
    w1f[(size_t)H1 * KPAD + base]  = h2;
}

// ---------------------------------------------------------------------------
// Kernel 2b: split w2 fp32 -> w2f[2][32][1024] fp16 (rows 20..31 zero)
// ---------------------------------------------------------------------------
__global__ void split2_w2_k(const float* __restrict__ w2, unsigned short* __restrict__ w2f) {
    const int o = blockIdx.y;                         // 0..31
    const int k = blockIdx.x * 256 + threadIdx.x;     // 0..1023
    float w = (o < H2) ? w2[(size_t)o * H1 + k] : 0.f;
    const unsigned short h1 = f2h_bits(w);
    const float r1 = w - h2f(h1);
    const unsigned short h2 = f2h_bits(r1 * 2048.0f);
    const size_t base = (size_t)o * H1 + k;
    w2f[base]                      = h1;
    w2f[(size_t)N2P * H1 + base]   = h2;
}

// ---------------------------------------------------------------------------
// Kernel 3: GEMM1 via MFMA fp16, 2-term split (term2 scaled 2^11).
//   Tile 128x128, BK=32, 4 waves (2x2), 16x16x32 f16 MFMA.
//   Separate accumulators per term; epilogue u1 = acc0 + acc1/2048.
// ---------------------------------------------------------------------------
__global__ __launch_bounds__(256, 2)
void gemm1_mfma_k(const uint32_t* __restrict__ bits_t,
                  const unsigned short* __restrict__ w1f,
                  float* __restrict__ u1) {
    __shared__ uint32_t AsU[128 * 16];        //  8 KB : [row][16 u32]
    __shared__ uint32_t BsU[2 * 128 * 16];    // 16 KB : [term][row(o)][16 u32]

    const int tid  = threadIdx.x;
    const int lane = tid & 63;
    const int wave = tid >> 6;
    const int wr = wave >> 1, wc = wave & 1;
    const int n0 = blockIdx.x * 128;          // x = n-tile -> XCD-exclusive B panel
    const int m0 = blockIdx.y * 128;
    const int l15 = lane & 15, g = lane >> 4;

    const unsigned short* bsrc0 =
        w1f + (size_t)(n0 + (lane >> 2)) * KPAD + (lane & 3) * 8;

    const int arow_w = tid & 127;
    const int ah     = tid >> 7;              // 0/1 (which 16-bit half)
    const int axor   = (arow_w >> 1) & 3;
    const int apos0  = (2 * ah) ^ axor;
    const int apos1  = (2 * ah + 1) ^ axor;

    f32x4 acc[2][4][4];
    const f32x4 fz = {0.f, 0.f, 0.f, 0.f};
    #pragma unroll
    for (int t = 0; t < 2; ++t)
        #pragma unroll
        for (int i = 0; i < 4; ++i)
            #pragma unroll
            for (int j = 0; j < 4; ++j) acc[t][i][j] = fz;

    int aoff[4], boff[4];
    #pragma unroll
    for (int mi = 0; mi < 4; ++mi) {
        const int ar = wr * 64 + mi * 16 + l15;
        aoff[mi] = ar * 16 + ((g ^ ((ar >> 1) & 3)) << 2);
    }
    #pragma unroll
    for (int ni = 0; ni < 4; ++ni) {
        const int br = wc * 64 + ni * 16 + l15;
        boff[ni] = br * 16 + (g << 2);
    }

    for (int kw = 0; kw < KW; ++kw) {
        __syncthreads();
        // ---- stage B: 16 global_load_lds x 16B, 4 per wave ----
        #pragma unroll
        for (int j = 0; j < 4; ++j) {
            const int e    = wave * 4 + j;    // 0..15
            const int term = e >> 3;
            const int ii   = e & 7;           // 16-row slab
            const unsigned short* src =
                bsrc0 + (size_t)(term * H1 + ii * 16) * KPAD + kw * 32;
            __builtin_amdgcn_global_load_lds(
                (const __attribute__((address_space(1))) uint32_t*)src,
                (__attribute__((address_space(3))) uint32_t*)&BsU[term * 2048 + ii * 256],
                16, 0, 0);
        }
        // ---- stage A: unpack one half-word per thread (fp16 0/1) ----
        {
            const uint32_t word = bits_t[(size_t)kw * M_PADN + m0 + arow_w];
            uint32_t v[8];
            #pragma unroll
            for (int i = 0; i < 8; ++i) {
                const int b0 = ah * 16 + 2 * i;
                v[i] = (((word >> b0) & 1u) ? 0x00003C00u : 0u) |
                       (((word >> (b0 + 1)) & 1u) ? 0x3C000000u : 0u);
            }
            *(uint4*)&AsU[arow_w * 16 + apos0 * 4] = make_uint4(v[0], v[1], v[2], v[3]);
            *(uint4*)&AsU[arow_w * 16 + apos1 * 4] = make_uint4(v[4], v[5], v[6], v[7]);
        }
        __syncthreads();

        half8 af[4];
        #pragma unroll
        for (int mi = 0; mi < 4; ++mi) af[mi] = *(const half8*)&AsU[aoff[mi]];
        #pragma unroll
        for (int term = 0; term < 2; ++term) {
            half8 bfv[4];
            #pragma unroll
            for (int ni = 0; ni < 4; ++ni)
                bfv[ni] = *(const half8*)&BsU[term * 2048 + boff[ni]];
            #pragma unroll
            for (int mi = 0; mi < 4; ++mi)
                #pragma unroll
                for (int ni = 0; ni < 4; ++ni)
                    acc[term][mi][ni] = __builtin_amdgcn_mfma_f32_16x16x32_f16(
                        af[mi], bfv[ni], acc[term][mi][ni], 0, 0, 0);
        }
    }

    // ---- epilogue: D layout col=lane&15, row=(lane>>4)*4+r ----
    #pragma unroll
    for (int mi = 0; mi < 4; ++mi) {
        const int mbase = m0 + wr * 64 + mi * 16 + g * 4;
        #pragma unroll
        for (int ni = 0; ni < 4; ++ni) {
            const int o = n0 + wc * 64 + ni * 16 + l15;
            #pragma unroll
            for (int r = 0; r < 4; ++r)
                u1[(size_t)(mbase + r) * H1 + o] =
                    acc[0][mi][ni][r] + acc[1][mi][ni][r] * INV2048;
        }
    }
}

// ---------------------------------------------------------------------------
// Kernel 4: fused psp1 + spike_dyn1 over T; writes s1 as fp16 (0 / 0x3C00)
// ---------------------------------------------------------------------------
__global__ void scan1_k(const float* __restrict__ u1, unsigned short* __restrict__ s1f) {
    const int lane = blockIdx.x * 64 + threadIdx.x;   // 0..16383 = b*1024+h
    const float CREF = -20.0f * CC_C;
    float p1 = 0.f, q1 = 0.f, pr = 0.f, qr = 0.f;
    float A[10], Bv[10];

#define STEP1(xv, tidx) {                                   \
        q1 = DD_C * (q1 + p1); p1 = DD_C * p1 + (xv);       \
        const float uu = CC_C * q1;                         \
        qr = DD_C * (qr + pr);                              \
        const float vv = uu + CREF * qr - THETA_C;          \
        const float ss = (vv >= 0.f) ? 1.f : 0.f;           \
        pr = DD_C * pr + ss;                                \
        s1f[(size_t)(tidx) * 16384 + lane] =                \
            (vv >= 0.f) ? (unsigned short)0x3C00 : (unsigned short)0; }

    #pragma unroll
    for (int j = 0; j < 10; ++j) A[j] = u1[(size_t)j * 16384 + lane];
    for (int it = 0; it < 25; ++it) {
        const int gB = 2 * it + 1;
        #pragma unroll
        for (int j = 0; j < 10; ++j) Bv[j] = u1[(size_t)(gB * 10 + j) * 16384 + lane];
        #pragma unroll
        for (int j = 0; j < 10; ++j) STEP1(A[j], (2 * it) * 10 + j);
        if (it < 24) {
            const int gA = 2 * it + 2;
            #pragma unroll
            for (int j = 0; j < 10; ++j) A[j] = u1[(size_t)(gA * 10 + j) * 16384 + lane];
        }
        #pragma unroll
        for (int j = 0; j < 10; ++j) STEP1(Bv[j], gB * 10 + j);
    }
#undef STEP1
}

// ---------------------------------------------------------------------------
// Kernel 5: GEMM2 via MFMA fp16: u2[m][o] = sum_h s1[m][h]*w2[o][h]
//   M tiles of 128 (63 blocks), N = 32 (2 frags), K = 1024, 2-term w2.
// ---------------------------------------------------------------------------
__global__ __launch_bounds__(256)
void gemm2_mfma_k(const unsigned short* __restrict__ s1f,
                  const unsigned short* __restrict__ w2f,
                  float* __restrict__ u2) {
    __shared__ uint32_t AsU[128 * 16];       // 8 KB : [row][16 u32]
    __shared__ uint32_t BsU[2 * 32 * 16];    // 4 KB : [term][o][16 u32]

    const int tid  = threadIdx.x;
    const int lane = tid & 63;
    const int wave = tid >> 6;
    const int m0 = blockIdx.x * 128;
    const int l15 = lane & 15, g = lane >> 4;

    f32x4 acc[2][2][2];
    const f32x4 fz = {0.f, 0.f, 0.f, 0.f};
    #pragma unroll
    for (int t = 0; t < 2; ++t)
        #pragma unroll
        for (int i = 0; i < 2; ++i)
            #pragma unroll
            for (int j = 0; j < 2; ++j) acc[t][i][j] = fz;

    int aoff[2], boff[2][2];
    #pragma unroll
    for (int mi = 0; mi < 2; ++mi) {
        const int ar = wave * 32 + mi * 16 + l15;
        aoff[mi] = ar * 16 + ((g ^ ((ar >> 1) & 3)) << 2);
    }
    #pragma unroll
    for (int term = 0; term < 2; ++term)
        #pragma unroll
        for (int ni = 0; ni < 2; ++ni) {
            const int br = ni * 16 + l15;
            boff[term][ni] = term * 512 + br * 16 + ((g ^ ((br >> 1) & 3)) << 2);
        }

    for (int kw = 0; kw < 32; ++kw) {
        __syncthreads();
        // ---- stage A: 128x32 fp16, 2 issues, source-side chunk swizzle ----
        #pragma unroll
        for (int i = 0; i < 2; ++i) {
            const int c   = i * 256 + tid;          // 16B chunk id
            const int row = c >> 2;
            const int kc  = c & 3;
            const unsigned short* src =
                s1f + (size_t)(m0 + row) * H1 + kw * 32 + (kc ^ ((row >> 1) & 3)) * 8;
            __builtin_amdgcn_global_load_lds(
                (const __attribute__((address_space(1))) uint32_t*)src,
                (__attribute__((address_space(3))) uint32_t*)&AsU[(i * 256 + wave * 64) * 4],
                16, 0, 0);
        }
        // ---- stage B: 2x32x32 fp16, 1 issue ----
        {
            const int c    = tid;                   // 0..255
            const int term = c >> 7;
            const int o    = (c >> 2) & 31;
            const int kc   = c & 3;
            const unsigned short* src =
                w2f + (size_t)(term * N2P + o) * H1 + kw * 32 + (kc ^ ((o >> 1) & 3)) * 8;
            __builtin_amdgcn_global_load_lds(
                (const __attribute__((address_space(1))) uint32_t*)src,
                (__attribute__((address_space(3))) uint32_t*)&BsU[wave * 256],
                16, 0, 0);
        }
        __syncthreads();

        half8 af[2];
        #pragma unroll
        for (int mi = 0; mi < 2; ++mi) af[mi] = *(const half8*)&AsU[aoff[mi]];
        #pragma unroll
        for (int term = 0; term < 2; ++term)
            #pragma unroll
            for (int ni = 0; ni < 2; ++ni) {
                const half8 bf = *(const half8*)&BsU[boff[term][ni]];
                #pragma unroll
                for (int mi = 0; mi < 2; ++mi)
                    acc[term][mi][ni] = __builtin_amdgcn_mfma_f32_16x16x32_f16(
                        af[mi], bf, acc[term][mi][ni], 0, 0, 0);
            }
    }

    #pragma unroll
    for (int mi = 0; mi < 2; ++mi) {
        const int mbase = m0 + wave * 32 + mi * 16 + g * 4;
        #pragma unroll
        for (int ni = 0; ni < 2; ++ni) {
            const int o = ni * 16 + l15;
            if (o < H2) {
                #pragma unroll
                for (int r = 0; r < 4; ++r)
                    u2[(size_t)(mbase + r) * H2 + o] =
                        acc[0][mi][ni][r] + acc[1][mi][ni][r] * INV2048;
            }
        }
    }
}

// ---------------------------------------------------------------------------
// Kernel 6: fused psp2 + spike_dyn2 (320 lanes) + transposed output write
// ---------------------------------------------------------------------------
__global__ void scan2_k(const float* __restrict__ u2, float* __restrict__ out) {
    const int lane = blockIdx.x * 64 + threadIdx.x;    // 0..319 = b*20 + o2
    if (lane >= 320) return;
    const float CREF = -20.0f * CC_C;
    float p1 = 0.f, q1 = 0.f, pr = 0.f, qr = 0.f;
    float A[10], Bv[10];

#define STEP2(xv, tidx) {                                   \
        q1 = DD_C * (q1 + p1); p1 = DD_C * p1 + (xv);       \
        const float uu = CC_C * q1;                         \
        qr = DD_C * (qr + pr);                              \
        const float vv = uu + CREF * qr - THETA_C;          \
        const float ss = (vv >= 0.f) ? 1.f : 0.f;           \
        pr = DD_C * pr + ss;                                \
        out[(size_t)lane * T_N + (tidx)] = ss; }

    #pragma unroll
    for (int j = 0; j < 10; ++j) A[j] = u2[(size_t)j * 320 + lane];
    for (int it = 0; it < 25; ++it) {
        const int gB = 2 * it + 1;
        #pragma unroll
        for (int j = 0; j < 10; ++j) Bv[j] = u2[(size_t)(gB * 10 + j) * 320 + lane];
        #pragma unroll
        for (int j = 0; j < 10; ++j) STEP2(A[j], (2 * it) * 10 + j);
        if (it < 24) {
            const int gA = 2 * it + 2;
            #pragma unroll
            for (int j = 0; j < 10; ++j) A[j] = u2[(size_t)(gA * 10 + j) * 320 + lane];
        }
        #pragma unroll
        for (int j = 0; j < 10; ++j) STEP2(Bv[j], gB * 10 + j);
    }
#undef STEP2
}

// ---------------------------------------------------------------------------
extern "C" void kernel_launch(void* const* d_in, const int* in_sizes, int n_in,
                              void* d_out, int out_size, void* d_ws, size_t ws_size,
                              hipStream_t stream) {
    const float* x  = (const float*)d_in[0];   // (16,2,50,63,500) binary
    const float* w1 = (const float*)d_in[1];   // (1024,6300)
    const float* w2 = (const float*)d_in[2];   // (20,1024)
    float* out = (float*)d_out;                // (16,20,500)

    char* ws = (char*)d_ws;
    size_t off = 0;
    uint32_t*       bits_t = (uint32_t*)(ws + off);       off += (size_t)KW * M_PADN * 4;       //  6.39 MB
    unsigned short* w1f    = (unsigned short*)(ws + off); off += (size_t)2 * H1 * KPAD * 2;     // 25.95 MB
    unsigned short* w2f    = (unsigned short*)(ws + off); off += (size_t)2 * N2P * H1 * 2;      //  0.13 MB
    float*          u1     = (float*)(ws + off);          off += (size_t)M_PADN * H1 * 4;       // 33.03 MB
    unsigned short* s1f    = (unsigned short*)(ws + off); off += (size_t)M_PADN * H1 * 2;       // 16.52 MB
    float*          u2     = (float*)(ws + off);          off += (size_t)M_PADN * H2 * 4;       //  0.65 MB
    (void)ws_size; (void)in_sizes; (void)n_in; (void)out_size;

    prep_bits_t_k <<<dim3(8, KW, B_N), 64,  0, stream>>>(x, bits_t);
    split2_w1_k   <<<dim3(25, H1),     256, 0, stream>>>(w1, w1f);
    split2_w2_k   <<<dim3(4, N2P),     256, 0, stream>>>(w2, w2f);
    gemm1_mfma_k  <<<dim3(8, 63),      256, 0, stream>>>(bits_t, w1f, u1);
    scan1_k       <<<256,              64,  0, stream>>>(u1, s1f);
    gemm2_mfma_k  <<<63,               256, 0, stream>>>(s1f, w2f, u2);
    scan2_k       <<<5,                64,  0, stream>>>(u2, out);
}